// Round 12
// baseline (141.938 us; speedup 1.0000x reference)
//
#include <hip/hip_runtime.h>

// SpatialIndependentDistribution, round 12: DIAGNOSTIC (counter surfacing).
// Exact R10 kernel, but grid 4096 with tile = blockIdx & 1023: 4 duplicate
// generations compute byte-identical results (idempotent same-value stores).
// Purpose: dispatch ~3-4x longer than the 42us harness fills -> hot kernel
// finally appears in rocprof top-5 with VGPR/VALUBusy/MfmaUtil/FETCH/WRITE,
// and the dur vs 4x19us tests inter-generation pipelining. Next round reverts.

#define NEG_HALF_LOG_2PI -0.91893853320467274f

typedef _Float16 f16x4 __attribute__((ext_vector_type(4)));
typedef __fp16   hf2   __attribute__((ext_vector_type(2)));
typedef float    f32x4 __attribute__((ext_vector_type(4)));

__device__ inline f16x4 pack_f16(f32x4 v) {
    hf2 p0 = __builtin_amdgcn_cvt_pkrtz(v[0], v[1]);
    hf2 p1 = __builtin_amdgcn_cvt_pkrtz(v[2], v[3]);
    f16x4 r;
    __builtin_memcpy(&r, &p0, 4);
    __builtin_memcpy((char*)&r + 4, &p1, 4);
    return r;
}

__device__ inline f16x4 relu_pack(f32x4 d) {
    hf2 p0 = __builtin_amdgcn_cvt_pkrtz(fmaxf(d[0], 0.0f), fmaxf(d[1], 0.0f));
    hf2 p1 = __builtin_amdgcn_cvt_pkrtz(fmaxf(d[2], 0.0f), fmaxf(d[3], 0.0f));
    f16x4 r;
    __builtin_memcpy(&r, &p0, 4);
    __builtin_memcpy((char*)&r + 4, &p1, 4);
    return r;
}

__global__ __launch_bounds__(256, 4) void spatial_main(
    const float* __restrict__ samples,   // [64,16,64,64]
    const float* __restrict__ n1_b1,     // [16]
    const float* __restrict__ n1_w2,     // [16,16]
    const float* __restrict__ n1_b2,     // [16]
    const float* __restrict__ n1_w3,     // [2,16]
    const float* __restrict__ n1_b3,     // [2]
    const float* __restrict__ w1,        // [15,16,16] zero-padded triangular
    const float* __restrict__ b1,        // [15,16]
    const float* __restrict__ w2,        // [15,16,16]
    const float* __restrict__ b2,        // [15,16]
    const float* __restrict__ w3,        // [15,2,16]
    const float* __restrict__ b3,        // [15,2]
    float* __restrict__ out)             // [64,64,64]
{
    __shared__ _Float16 fA[45 * 256];    // 23040 B
    __shared__ float    fC[15 * 2 * 16]; // 1920 B

    const int tid   = threadIdx.x;
    const int lane  = tid & 63;
    const int wv    = tid >> 6;
    const int q     = lane >> 4;
    const int col   = lane & 15;
    const int lane4 = lane << 2;
    const int q4    = q << 2;
    const int roff  = col * 16 + q4;

    // ---- stage fA, destination-ordered: one matrix per wave-iteration ----
    for (int j = tid; j < 45 * 64; j += 256) {
        int m  = j >> 6;
        int ln = j & 63;
        int r  = ln & 15;
        int c  = ln >> 4;
        f32x4 v;
        if (m < 15) {
            v = *(const f32x4*)(w1 + m * 256 + r * 16 + (c << 2));
        } else if (m < 30) {
            v = *(const f32x4*)(w2 + (m - 15) * 256 + r * 16 + (c << 2));
        } else {
            v = (f32x4){0.f, 0.f, 0.f, 0.f};
            if ((r & 3) < 2)
                v = *(const f32x4*)(w3 + (m - 30) * 32 + ((r & 1) << 4) + (c << 2));
        }
        *(f16x4*)&fA[(j << 2)] = pack_f16(v);
    }
    for (int j = tid; j < 15 * 2 * 16; j += 256) {
        int s = j >> 5, layer = (j >> 4) & 1, o = j & 15;
        fC[j] = layer ? b2[s * 16 + o] : b1[s * 16 + o];
    }

    // DIAGNOSTIC: 4 generations of duplicate tiles
    const int tile  = blockIdx.x & 1023;
    const int pbase = tile * 256 + wv * 64;
    const int b     = pbase >> 12;
    const int hw    = pbase & 4095;
    const float* xw = samples + ((size_t)b << 16) + hw;

    float px[16];
    #pragma unroll
    for (int c = 0; c < 16; ++c) px[c] = xw[(c << 12) + lane];

    f16x4 bx[4];
    #pragma unroll
    for (int ch = 0; ch < 4; ++ch)
        #pragma unroll
        for (int i = 0; i < 4; ++i)
            bx[ch][i] = (_Float16)xw[((q4 + i) << 12) + (ch << 4) + col];

    float accz, accl;
    {
        f32x4 c1h = *(const f32x4*)(n1_b1 + q4);
        f16x4 h1h = relu_pack(c1h);
        f16x4 a2h = pack_f16(*(const f32x4*)(n1_w2 + roff));
        f32x4 c2h = *(const f32x4*)(n1_b2 + q4);
        f32x4 d2h = __builtin_amdgcn_mfma_f32_16x16x16f16(a2h, h1h, c2h, 0, 0, 0);
        f16x4 h2h = relu_pack(d2h);
        f32x4 v3h = {0.f, 0.f, 0.f, 0.f};
        if ((col & 3) < 2) v3h = *(const f32x4*)(n1_w3 + ((col & 1) << 4) + q4);
        f16x4 a3h = pack_f16(v3h);
        f32x4 c3h = {n1_b3[0], n1_b3[1], 0.0f, 0.0f};
        f32x4 d3h = __builtin_amdgcn_mfma_f32_16x16x16f16(a3h, h2h, c3h, 0, 0, 0);
        float ls = d3h[1];
        float z0 = (px[0] - d3h[0]) * __expf(-ls);
        accz = z0 * z0;
        accl = ls;
    }

    __syncthreads();

    #pragma unroll
    for (int s = 0; s < 15; ++s) {
        f16x4 a1 = *(const f16x4*)&fA[(s)      * 256 + lane4];
        f16x4 a2 = *(const f16x4*)&fA[(15 + s) * 256 + lane4];
        f16x4 a3 = *(const f16x4*)&fA[(30 + s) * 256 + lane4];
        f32x4 c1 = *(const f32x4*)&fC[(s * 2 + 0) * 16 + q4];
        f32x4 c2 = *(const f32x4*)&fC[(s * 2 + 1) * 16 + q4];
        f32x4 c3 = {b3[s * 2 + 0], b3[s * 2 + 1], 0.0f, 0.0f};

        float loc_q[4], ls_q[4];
        #pragma unroll
        for (int ch = 0; ch < 4; ++ch) {
            f32x4 d1 = __builtin_amdgcn_mfma_f32_16x16x16f16(a1, bx[ch], c1, 0, 0, 0);
            f16x4 h1 = relu_pack(d1);
            f32x4 d2 = __builtin_amdgcn_mfma_f32_16x16x16f16(a2, h1, c2, 0, 0, 0);
            f16x4 h2 = relu_pack(d2);
            f32x4 d3 = __builtin_amdgcn_mfma_f32_16x16x16f16(a3, h2, c3, 0, 0, 0);
            loc_q[ch] = d3[0];
            ls_q[ch]  = d3[1];
        }
        float loc = q == 0 ? loc_q[0] : q == 1 ? loc_q[1] : q == 2 ? loc_q[2] : loc_q[3];
        float ls  = q == 0 ? ls_q[0]  : q == 1 ? ls_q[1]  : q == 2 ? ls_q[2]  : ls_q[3];
        float z   = (px[s + 1] - loc) * __expf(-ls);
        accz = fmaf(z, z, accz);
        accl += ls;
    }

    out[pbase + lane] = fmaf(-0.5f, accz, 16.0f * NEG_HALF_LOG_2PI - accl);
}

extern "C" void kernel_launch(void* const* d_in, const int* in_sizes, int n_in,
                              void* d_out, int out_size, void* d_ws, size_t ws_size,
                              hipStream_t stream) {
    const float* samples = (const float*)d_in[0];
    const float* n1_b1   = (const float*)d_in[2];
    const float* n1_w2   = (const float*)d_in[3];
    const float* n1_b2   = (const float*)d_in[4];
    const float* n1_w3   = (const float*)d_in[5];
    const float* n1_b3   = (const float*)d_in[6];
    const float* w1      = (const float*)d_in[7];
    const float* b1      = (const float*)d_in[8];
    const float* w2      = (const float*)d_in[9];
    const float* b2      = (const float*)d_in[10];
    const float* w3      = (const float*)d_in[11];
    const float* b3      = (const float*)d_in[12];
    float* out = (float*)d_out;

    // DIAGNOSTIC grid: 4096 blocks = 4 idempotent generations of the 1024 tiles
    spatial_main<<<dim3(4096), dim3(256), 0, stream>>>(
        samples, n1_b1, n1_w2, n1_b2, n1_w3, n1_b3,
        w1, b1, w2, b2, w3, b3, out);
}